// Round 12
// baseline (158.160 us; speedup 1.0000x reference)
//
#include <hip/hip_runtime.h>
#include <hip/hip_bf16.h>

#define TT 2048
#define DD 128
#define NB 16
#define KVB 32            // keys per tile
#define NTILE 64          // 32-key tiles per sequence
#define TILE_BYTES 8192   // 32x128 bf16, fragment-ordered

typedef __bf16 bf16x8 __attribute__((ext_vector_type(8)));
typedef float f32x4 __attribute__((ext_vector_type(4)));
typedef float f32x16 __attribute__((ext_vector_type(16)));

__device__ __forceinline__ float warp16_sum(float v) {
    v += __shfl_xor(v, 1);
    v += __shfl_xor(v, 2);
    v += __shfl_xor(v, 4);
    v += __shfl_xor(v, 8);
    return v;
}
__device__ __forceinline__ float bf2f(unsigned int u16) {
    union { unsigned int i; float f; } x; x.i = u16 << 16; return x.f;
}
__device__ __forceinline__ unsigned int pk2(float lo, float hi) {
    unsigned short a = __builtin_bit_cast(unsigned short, (__bf16)lo);
    unsigned short b = __builtin_bit_cast(unsigned short, (__bf16)hi);
    return (unsigned int)a | ((unsigned int)b << 16);
}
__device__ __forceinline__ bf16x8 frag4(unsigned int a, unsigned int b,
                                        unsigned int c, unsigned int d) {
    uint4 u = make_uint4(a, b, c, d);
    return __builtin_bit_cast(bf16x8, u);
}
__device__ __forceinline__ f32x16 z16() {
    f32x16 v;
    #pragma unroll
    for (int i = 0; i < 16; ++i) v[i] = 0.f;
    return v;
}
__device__ __forceinline__ int ncof(int qb, int C) {
    return (4 * qb + 4 + C - 1) / C;
}

// 1/sqrt(128) * log2(e): folded into Q so softmax is exp2 directly
#define QSCALE 0.12751744485f
#define PITCH 136   // LDS stage row pitch (floats); breaks bank alignment

// ---------------- prepass: K/V/Q -> fragment-ordered bf16 (all-coalesced IO) ----
// K tile: frag kc (0..7) at kc*1024; entry (hi*32+key)*16 = K[key][kc*16+8hi..+8]
// V tile: frag f=dg*2+ks at f*1024; entry (hi*32+ln)*16 = V[ks*16+8hi+j][dg*32+ln]
// Q frags: per (b,qb,w): 16 frags (kc,hi) of 512B; entry ln*16 = Q[ln][kc*16+8hi..]
__global__ __launch_bounds__(256) void prepass(
    const float* __restrict__ K, const float* __restrict__ V,
    const float* __restrict__ Q,
    char* __restrict__ KB, char* __restrict__ VTB, char* __restrict__ QF)
{
    __shared__ float S[32 * PITCH];
    const int t = blockIdx.x;
    const int b = blockIdx.y;
    const int tid = threadIdx.x;
    const int sub = tid >> 5;   // 0..7
    const int ln  = tid & 31;

    auto stage = [&](const float* src) {     // 16KB contiguous -> LDS [32][PITCH]
        const float4* g = (const float4*)src;
        #pragma unroll
        for (int i = 0; i < 4; ++i) {
            int f = i * 256 + tid;           // 0..1023 float4s
            int row = f >> 5, c4 = (f & 31) * 4;
            *(float4*)(&S[row * PITCH + c4]) = g[f];
        }
    };
    auto cv8 = [&](const float* s, float sc) {
        bf16x8 h;
        #pragma unroll
        for (int j = 0; j < 8; ++j) h[j] = (__bf16)(s[j] * sc);
        return h;
    };

    // ---- K ----
    stage(K + ((size_t)b * TT + t * KVB) * DD);
    __syncthreads();
    {
        char* kdst = KB + (size_t)(b * NTILE + t) * TILE_BYTES;
        #pragma unroll
        for (int hi = 0; hi < 2; ++hi)
            *(bf16x8*)(kdst + sub * 1024 + (hi * 32 + ln) * 16) =
                cv8(&S[ln * PITCH + sub * 16 + 8 * hi], 1.0f);
    }
    __syncthreads();
    // ---- V (transpose out of LDS) ----
    stage(V + ((size_t)b * TT + t * KVB) * DD);
    __syncthreads();
    {
        char* vdst = VTB + (size_t)(b * NTILE + t) * TILE_BYTES;
        const int dg = sub >> 1, ks = sub & 1;
        #pragma unroll
        for (int hi = 0; hi < 2; ++hi) {
            bf16x8 h;
            #pragma unroll
            for (int j = 0; j < 8; ++j)
                h[j] = (__bf16)S[(ks * 16 + 8 * hi + j) * PITCH + dg * 32 + ln];
            *(bf16x8*)(vdst + sub * 1024 + (hi * 32 + ln) * 16) = h;
        }
    }
    __syncthreads();
    // ---- Q (rows t*32..+31 = q-block t>>2, wave t&3) ----
    stage(Q + ((size_t)b * TT + t * KVB) * DD);
    __syncthreads();
    {
        char* qdst = QF + ((size_t)((b * 16 + (t >> 2)) * 4 + (t & 3)) * 16) * 512;
        #pragma unroll
        for (int hi = 0; hi < 2; ++hi)
            *(bf16x8*)(qdst + sub * 1024 + hi * 512 + ln * 16) =
                cv8(&S[ln * PITCH + sub * 16 + 8 * hi], QSCALE);
    }
}

// ---------------- main: LDS-free, barrier-free; 4 independent waves/block ------
// Each wave owns 32 q-rows, streams frag-ordered K/V tiles L2 -> registers.
// Swapped QK^T (A=K, B=Q) 32x32x16; softmax lane-local; P in registers.
// Uniform short chunks (CHUNK tiles) -> equal-length blocks, short critical path.
__global__ __launch_bounds__(256) void attn_main(
    const char* __restrict__ QF,
    const char* __restrict__ KB, const char* __restrict__ VTB,
    float* __restrict__ O, char* __restrict__ SLOTS,
    int CHUNK, int SLOTS_PER_B)
{
    const int b = blockIdx.x;                // b fastest: 2 seqs per XCD L2
    // decode slot -> (qb, z), heavy qb first
    int s = blockIdx.y;
    int qb = 0, z = 0, acc = 0;
    for (int q = 15; q >= 0; --q) {
        int c = ncof(q, CHUNK);
        if (s < acc + c) { qb = q; z = s - acc; break; }
        acc += c;
    }
    const int ntile = 4 * qb + 4;
    const int nc = ncof(qb, CHUNK);
    const int t0 = (int)(((long)z * ntile) / nc);
    const int t1 = (int)(((long)(z + 1) * ntile) / nc);

    const int tid  = threadIdx.x;
    const int lane = tid & 63;
    const int w    = tid >> 6;               // wave 0..3 (independent)
    const int ln   = lane & 31;
    const int hi   = lane >> 5;
    const int qrow0 = qb * 128 + w * 32;
    const int q_abs = qrow0 + ln;

    // ---- Q fragments: coalesced b128 loads ----
    const char* qfb = QF + (((size_t)(b * 16 + qb) * 4 + w) * 16 + hi) * 512 + ln * 16;
    bf16x8 qf[8];
    #pragma unroll
    for (int kc = 0; kc < 8; ++kc)
        qf[kc] = *(const bf16x8*)(qfb + kc * 1024);

    f32x16 o[4];
    #pragma unroll
    for (int dg = 0; dg < 4; ++dg) o[dg] = z16();
    float lsum = 0.f;

    const char* kbase = KB  + (size_t)b * NTILE * TILE_BYTES;
    const char* vbase = VTB + (size_t)b * NTILE * TILE_BYTES;

    for (int t = t0; t < t1; ++t) {
        const int kb = t * KVB;
        if (kb > qrow0 + 31) break;          // all later tiles masked too
        const bool edge = (kb + 31 > qrow0);
        const char* kt = kbase + (size_t)t * TILE_BYTES + lane * 16;
        const char* vt = vbase + (size_t)t * TILE_BYTES + lane * 16;

        // all 16 frag loads issued up front (coalesced 1KB each, L2-resident)
        bf16x8 kf[8], vf[8];
        #pragma unroll
        for (int kc = 0; kc < 8; ++kc)
            kf[kc] = *(const bf16x8*)(kt + kc * 1024);
        #pragma unroll
        for (int f = 0; f < 8; ++f)
            vf[f] = *(const bf16x8*)(vt + f * 1024);

        // ---- QK^T (swapped): S^T[key][q], two interleaved chains ----
        f32x16 a0 = z16(), a1 = z16();
        #pragma unroll
        for (int kc = 0; kc < 8; kc += 2) {
            a0 = __builtin_amdgcn_mfma_f32_32x32x16_bf16(kf[kc],     qf[kc],     a0, 0, 0, 0);
            a1 = __builtin_amdgcn_mfma_f32_32x32x16_bf16(kf[kc + 1], qf[kc + 1], a1, 0, 0, 0);
        }
        // ---- exp2 (no-max softmax; scale folded into Q), mask on edges ----
        float p[16];
        float ls0 = 0.f, ls1 = 0.f;
        #pragma unroll
        for (int reg = 0; reg < 16; ++reg) {
            int key_abs = kb + (reg & 3) + 8 * (reg >> 2) + 4 * hi;
            float pe = __builtin_amdgcn_exp2f(a0[reg] + a1[reg]);
            if (edge && key_abs > q_abs) pe = 0.f;
            p[reg] = pe;
            if (reg & 1) ls1 += pe; else ls0 += pe;
        }
        lsum += ls0 + ls1;
        // ---- build PV A-frags in registers (pack + cross-half swap) ----
        unsigned int wd[8], xr[8];
        #pragma unroll
        for (int i = 0; i < 8; ++i) wd[i] = pk2(p[2 * i], p[2 * i + 1]);
        #pragma unroll
        for (int i = 0; i < 8; ++i) xr[i] = __shfl_xor(wd[i], 32);
        bf16x8 pa0 = hi ? frag4(xr[2], xr[3], wd[2], wd[3])
                        : frag4(wd[0], wd[1], xr[0], xr[1]);
        bf16x8 pa1 = hi ? frag4(xr[6], xr[7], wd[6], wd[7])
                        : frag4(wd[4], wd[5], xr[4], xr[5]);
        // ---- PV: O[q][d] += P(32x32) * V(32x128) ----
        #pragma unroll
        for (int dg = 0; dg < 4; ++dg) {
            o[dg] = __builtin_amdgcn_mfma_f32_32x32x16_bf16(pa0, vf[dg * 2],     o[dg], 0, 0, 0);
            o[dg] = __builtin_amdgcn_mfma_f32_32x32x16_bf16(pa1, vf[dg * 2 + 1], o[dg], 0, 0, 0);
        }
    }

    const float ltot = lsum + __shfl_xor(lsum, 32);

    if (nc == 1) {
        const float inv = 1.0f / ltot;
        float* op = O + ((size_t)b * TT + qrow0) * DD;
        #pragma unroll
        for (int reg = 0; reg < 16; ++reg) {
            int qr = (reg & 3) + 8 * (reg >> 2) + 4 * hi;
            float iv = __shfl(inv, qr);
            #pragma unroll
            for (int dg = 0; dg < 4; ++dg)
                op[(size_t)qr * DD + dg * 32 + ln] = o[dg][reg] * iv;
        }
    } else {
        // ---- partial: [128][128] bf16 raw sums + [128] fp32 l ----
        int soff = 0;
        for (int q = 0; q < qb; ++q) {
            int c = ncof(q, CHUNK);
            if (c >= 2) soff += c;
        }
        char* slot = SLOTS + (size_t)(b * SLOTS_PER_B + soff + z) * 33280;
        unsigned short* so = (unsigned short*)slot;
        float* sl = (float*)(slot + 32768);
        #pragma unroll
        for (int reg = 0; reg < 16; ++reg) {
            int row = w * 32 + (reg & 3) + 8 * (reg >> 2) + 4 * hi;
            #pragma unroll
            for (int dg = 0; dg < 4; ++dg)
                so[row * 128 + dg * 32 + ln] =
                    __builtin_bit_cast(unsigned short, (__bf16)o[dg][reg]);
        }
        if (hi == 0) sl[w * 32 + ln] = ltot;
    }
}

__global__ __launch_bounds__(256) void attn_combine(
    const char* __restrict__ SLOTS, float* __restrict__ O,
    int CHUNK, int SLOTS_PER_B)
{
    const int qb = blockIdx.x;
    const int b  = blockIdx.y;
    const int nc = ncof(qb, CHUNK);
    if (nc < 2) return;
    int off = 0;
    for (int q = 0; q < qb; ++q) {
        int c = ncof(q, CHUNK);
        if (c >= 2) off += c;
    }
    const int row  = threadIdx.x >> 1;
    const int half = (threadIdx.x & 1) * 64;
    const char* base = SLOTS + (size_t)(b * SLOTS_PER_B + off) * 33280;

    float l = 0.f;
    for (int c = 0; c < nc; ++c)
        l += *(const float*)(base + (size_t)c * 33280 + 32768 + row * 4);
    float inv = 1.0f / l;

    float* op = O + ((size_t)b * TT + qb * 128 + row) * DD + half;
    #pragma unroll
    for (int g = 0; g < 8; ++g) {
        f32x4 a0 = (f32x4){0.f,0.f,0.f,0.f}, a1 = (f32x4){0.f,0.f,0.f,0.f};
        for (int c = 0; c < nc; ++c) {
            const uint4 u = *(const uint4*)(base + (size_t)c * 33280 + row * 256 + half * 2 + g * 16);
            a0[0] += bf2f(u.x & 0xffffu); a0[1] += bf2f(u.x >> 16);
            a0[2] += bf2f(u.y & 0xffffu); a0[3] += bf2f(u.y >> 16);
            a1[0] += bf2f(u.z & 0xffffu); a1[1] += bf2f(u.z >> 16);
            a1[2] += bf2f(u.w & 0xffffu); a1[3] += bf2f(u.w >> 16);
        }
        float4 r0, r1;
        r0.x=a0[0]*inv; r0.y=a0[1]*inv; r0.z=a0[2]*inv; r0.w=a0[3]*inv;
        r1.x=a1[0]*inv; r1.y=a1[1]*inv; r1.z=a1[2]*inv; r1.w=a1[3]*inv;
        *(float4*)(op + g * 8)     = r0;
        *(float4*)(op + g * 8 + 4) = r1;
    }
}

// ---------------- fallback (ws too small): round-3 proven kernel, no split ------
__global__ __launch_bounds__(256) void attn_fb(
    const float* __restrict__ Q, const float* __restrict__ K,
    const float* __restrict__ V, float* __restrict__ O)
{
    __shared__ __align__(16) unsigned short Klds[2][64 * 128];
    __shared__ __align__(16) unsigned short Vsh[2][128 * 64];
    __shared__ __align__(16) unsigned short Plds[4][16 * 64];
    typedef __bf16 bf16x4 __attribute__((ext_vector_type(4)));

    const int qb = 31 - blockIdx.x;
    const int b  = blockIdx.y;
    const int ntile = qb + 1;
    const int tid  = threadIdx.x;
    const int lane = tid & 63;
    const int w    = tid >> 6;
    const int x    = lane & 15;
    const int hi   = lane >> 4;
    const int qrow0 = qb * 64 + w * 16;

    const float* qp    = Q + ((size_t)b * TT + qrow0) * DD;
    const float* kbase = K + (size_t)b * TT * DD;
    const float* vbase = V + (size_t)b * TT * DD;
    const float SCALE = 0.08838834764831845f;

    const int krow = tid >> 5;
    const int d4   = (tid & 31) * 4;
    const int dd   = tid & 127;
    const int g    = tid >> 7;

    bf16x8 qf[4];
    #pragma unroll
    for (int kc = 0; kc < 4; ++kc) {
        const float4* s0 = (const float4*)(qp + x * DD + kc * 32 + 8 * hi);
        float4 f0 = s0[0], f1 = s0[1];
        bf16x8 t;
        t[0]=(__bf16)f0.x; t[1]=(__bf16)f0.y; t[2]=(__bf16)f0.z; t[3]=(__bf16)f0.w;
        t[4]=(__bf16)f1.x; t[5]=(__bf16)f1.y; t[6]=(__bf16)f1.z; t[7]=(__bf16)f1.w;
        qf[kc] = t;
    }
    f32x4 o[8];
    #pragma unroll
    for (int nt = 0; nt < 8; ++nt) o[nt] = (f32x4){0.f,0.f,0.f,0.f};
    float lsum[4] = {0.f,0.f,0.f,0.f};
    float4 kreg[8];
    float  vreg[32];

    auto LOAD = [&](int t) {
        const float* kp = kbase + (size_t)(t * 64) * DD;
        const float* vp = vbase + (size_t)(t * 64) * DD;
        #pragma unroll
        for (int it = 0; it < 8; ++it)
            kreg[it] = *(const float4*)(kp + (size_t)(it * 8 + krow) * DD + d4);
        #pragma unroll
        for (int j = 0; j < 32; ++j)
            vreg[j] = vp[(size_t)(g * 32 + j) * DD + dd];
    };
    auto WRITE = [&](int buf) {
        char* kb8 = (char*)Klds[buf];
        #pragma unroll
        for (int it = 0; it < 8; ++it) {
            int key = it * 8 + krow;
            float4 f = kreg[it];
            bf16x4 h;
            h[0]=(__bf16)f.x; h[1]=(__bf16)f.y; h[2]=(__bf16)f.z; h[3]=(__bf16)f.w;
            *(bf16x4*)(kb8 + key * 256 + ((d4 * 2) ^ ((key & 7) << 4))) = h;
        }
        char* vb8 = (char*)Vsh[buf];
        #pragma unroll
        for (int m4 = 0; m4 < 4; ++m4) {
            bf16x8 h;
            #pragma unroll
            for (int j = 0; j < 8; ++j) h[j] = (__bf16)vreg[m4 * 8 + j];
            *(bf16x8*)(vb8 + dd * 128 + ((g * 64 + m4 * 16) ^ ((dd & 7) << 4))) = h;
        }
    };

    LOAD(0); WRITE(0);
    int cur = 0;
    char* pmine = (char*)Plds[w];

    for (int t = 0; t < ntile; ++t) {
        const int kb = t * 64;
        __syncthreads();
        if (t + 1 < ntile) LOAD(t + 1);

        const bool diag  = (t == qb);
        const int  ntmax = diag ? w : 3;
        const char* kb8  = (const char*)Klds[cur];
        float p[4][4];
        #pragma unroll
        for (int nt = 0; nt < 4; ++nt) {
            int key = nt * 16 + x;
            if (nt <= ntmax) {
                f32x4 acc = (f32x4){0.f,0.f,0.f,0.f};
                #pragma unroll
                for (int kc = 0; kc < 4; ++kc) {
                    int off = key * 256 + ((kc * 64 + 16 * hi) ^ ((key & 7) << 4));
                    bf16x8 bfr = *(const bf16x8*)(kb8 + off);
                    acc = __builtin_amdgcn_mfma_f32_16x16x32_bf16(qf[kc], bfr, acc, 0, 0, 0);
                }
                #pragma unroll
                for (int r = 0; r < 4; ++r) {
                    bool msk = diag && (kb + key > qrow0 + 4 * hi + r);
                    float pe = msk ? 0.f : __expf(acc[r] * SCALE);
                    p[nt][r] = pe;
                    lsum[r] += pe;
                }
            } else {
                #pragma unroll
                for (int r = 0; r < 4; ++r) p[nt][r] = 0.f;
            }
        }
        #pragma unroll
        for (int nt = 0; nt < 4; ++nt)
            #pragma unroll
            for (int r = 0; r < 4; ++r) {
                int q = 4 * hi + r;
                *(unsigned short*)(pmine + q * 128 + (((nt * 16 + x) * 2) ^ ((q & 7) << 4))) =
                    __builtin_bit_cast(unsigned short, (__bf16)p[nt][r]);
            }
        const char* vb8 = (const char*)Vsh[cur];
        #pragma unroll
        for (int kc = 0; kc < 2; ++kc) {
            bf16x8 af = *(const bf16x8*)(pmine + x * 128 + ((kc * 64 + 16 * hi) ^ ((x & 7) << 4)));
            #pragma unroll
            for (int nt = 0; nt < 8; ++nt) {
                int d = nt * 16 + x;
                bf16x8 bfr = *(const bf16x8*)(vb8 + d * 128 + ((kc * 64 + 16 * hi) ^ ((d & 7) << 4)));
                o[nt] = __builtin_amdgcn_mfma_f32_16x16x32_bf16(af, bfr, o[nt], 0, 0, 0);
            }
        }
        if (t + 1 < ntile) WRITE(cur ^ 1);
        cur ^= 1;
    }
    float* op = O + ((size_t)b * TT + qrow0) * DD;
    #pragma unroll
    for (int r = 0; r < 4; ++r) {
        float lr = warp16_sum(lsum[r]);
        float inv = 1.0f / lr;
        #pragma unroll
        for (int nt = 0; nt < 8; ++nt)
            op[(size_t)(4 * hi + r) * DD + nt * 16 + x] = o[nt][r] * inv;
    }
}

extern "C" void kernel_launch(void* const* d_in, const int* in_sizes, int n_in,
                              void* d_out, int out_size, void* d_ws, size_t ws_size,
                              hipStream_t stream) {
    const float* q = (const float*)d_in[0];
    const float* k = (const float*)d_in[1];
    const float* v = (const float*)d_in[2];
    float* out = (float*)d_out;

    const size_t KVBYTES = (size_t)NB * NTILE * TILE_BYTES;   // 8.39 MB each
    const size_t QFBYTES = (size_t)NB * TT * DD * 2;          // 8.39 MB
    const size_t PRE = 2 * KVBYTES + QFBYTES;                 // 25.17 MB

    auto slotsPerB = [](int C) {       // partial slots (nc>=2)
        int s = 0;
        for (int qb = 0; qb < 16; ++qb) {
            int nc = (4 * qb + 4 + C - 1) / C;
            if (nc >= 2) s += nc;
        }
        return s;
    };
    auto blocksPerB = [](int C) {      // all chunk-blocks
        int s = 0;
        for (int qb = 0; qb < 16; ++qb) s += (4 * qb + 4 + C - 1) / C;
        return s;
    };

    char* kb    = (char*)d_ws;
    char* vtb   = kb + KVBYTES;
    char* qf    = vtb + KVBYTES;
    char* slots = qf + QFBYTES;

    auto launchTier = [&](int CHUNK) {
        int spb = slotsPerB(CHUNK);
        prepass<<<dim3(NTILE, NB), 256, 0, stream>>>(k, v, q, kb, vtb, qf);
        attn_main<<<dim3(NB, blocksPerB(CHUNK)), 256, 0, stream>>>(qf, kb, vtb, out, slots, CHUNK, spb);
        attn_combine<<<dim3(16, NB), 256, 0, stream>>>(slots, out, CHUNK, spb);
    };

    bool done = false;
    const int tiers[5] = {4, 6, 8, 12, 16};
    for (int i = 0; i < 5 && !done; ++i) {
        int C = tiers[i];
        size_t need = PRE + (size_t)NB * slotsPerB(C) * 33280;
        if (ws_size >= need) { launchTier(C); done = true; }
    }
    if (!done) {
        if (ws_size >= PRE) {           // 25.2 MB, no split
            prepass<<<dim3(NTILE, NB), 256, 0, stream>>>(k, v, q, kb, vtb, qf);
            attn_main<<<dim3(NB, 16), 256, 0, stream>>>(qf, kb, vtb, out, slots, 64, 0);
        } else {
            attn_fb<<<dim3(32, NB), 256, 0, stream>>>(q, k, v, out);
        }
    }
}